// Round 6
// baseline (174.846 us; speedup 1.0000x reference)
//
#include <hip/hip_runtime.h>
#include <hip/hip_fp16.h>
#include <cstdint>

// Problem constants (from reference)
#define N_NODES   50000
#define N_IN      512
#define HIDDEN    64
#define N_CLASSES 40
#define N_EDGES   800000

// Radix build parameters
#define G_BLOCKS  200                 // blocks in hist/scatter passes
#define EPB       4000                // edges per block (G_BLOCKS*EPB == N_EDGES)
#define NBINS     196                 // ceil(50000/256), bin = node >> 8
#define SCAN_N    (NBINS * G_BLOCKS)  // 39200
#define SCAN_NB   ((SCAN_N + 1023) / 1024)   // 39

// Workspace layout (byte offsets, 16B-aligned)
#define OFF_HA    0u          // 50000*64*2 bf16 = 6,400,000
#define OFF_HB    6400000u    // 6,400,000
#define OFF_DIS   12800000u   // 50000 floats = 200,000
#define OFF_OFFS  13000000u   // 50001 ints = 200,004 -> pad 200,016
#define OFF_HISTC 13200016u   // 39200 ints = 156,800
#define OFF_HISTR 13356816u   // 39200 ints = 156,800
#define OFF_BSUM  13513616u   // 128 ints = 512
#define OFF_COLS  13514128u   // 800000 u32 packed (r | c<<16) = 3,200,000
#define OFF_ROWS  16714128u   // 800000 ints = 3,200,000
#define OFF_EPACK 19914128u   // 800000 u32 (fp16 norm | src) = 3,200,000
#define OFF_W1T   23114128u   // 64*512 bf16 = 65,536
#define OFF_W2T   23179664u   // 64*64 bf16 = 8,192
// total ~23.2 MB

typedef __attribute__((ext_vector_type(8))) short short8_t;
typedef __attribute__((ext_vector_type(4))) float f32x4;

__device__ __forceinline__ ushort f2bf(float f) {
    uint u = __float_as_uint(f);
    uint r = (u + 0x7FFFu + ((u >> 16) & 1u)) >> 16;   // RNE
    return (ushort)r;
}
__device__ __forceinline__ float bf2f(ushort h) {
    return __uint_as_float((uint)h << 16);
}

// ---- stage 1: per-block coarse histograms (LDS only, no global atomics) ----
__global__ __launch_bounds__(256) void hist_k(const int* __restrict__ erow,
                                              const int* __restrict__ ecol,
                                              int* __restrict__ histC,
                                              int* __restrict__ histR) {
    __shared__ int hc[NBINS], hr[NBINS];
    int t = threadIdx.x, b = blockIdx.x;
    if (t < NBINS) { hc[t] = 0; hr[t] = 0; }
    __syncthreads();
    int s = b * EPB;
    for (int i = s + t; i < s + EPB; i += 256) {
        atomicAdd(&hc[ecol[i] >> 8], 1);
        atomicAdd(&hr[erow[i] >> 8], 1);
    }
    __syncthreads();
    if (t < NBINS) {
        histC[t * G_BLOCKS + b] = hc[t];   // [bin][block] layout for bin-major scan
        histR[t * G_BLOCKS + b] = hr[t];
    }
}

// ---- exclusive scan over histC (y=0) and histR (y=1), in-place ----
__global__ __launch_bounds__(256) void scan1(int* __restrict__ histC,
                                             int* __restrict__ histR,
                                             int* __restrict__ bsum, int n) {
    int* a  = blockIdx.y ? histR : histC;
    int* bs = bsum + blockIdx.y * 64;
    int t = threadIdx.x;
    int g = blockIdx.x * 1024 + t * 4;
    int v[4];
#pragma unroll
    for (int i = 0; i < 4; i++) v[i] = (g + i < n) ? a[g + i] : 0;
    int s = v[0] + v[1] + v[2] + v[3];
    int lane = t & 63, wid = t >> 6;
    int x = s;
#pragma unroll
    for (int d = 1; d < 64; d <<= 1) {
        int y = __shfl_up(x, d);
        if (lane >= d) x += y;
    }
    __shared__ int wt[4];
    if (lane == 63) wt[wid] = x;
    __syncthreads();
    int wo = 0;
    for (int w = 0; w < wid; w++) wo += wt[w];
    int run = wo + x - s;
#pragma unroll
    for (int i = 0; i < 4; i++) {
        if (g + i < n) a[g + i] = run;
        run += v[i];
    }
    if (t == 255) bs[blockIdx.x] = wo + x;
}

__global__ void scan2(int* bsum, int nb) {
    int* bs = bsum + blockIdx.x * 64;
    int lane = threadIdx.x;   // 64 threads
    int v = (lane < nb) ? bs[lane] : 0;
    int x = v;
#pragma unroll
    for (int d = 1; d < 64; d <<= 1) {
        int y = __shfl_up(x, d);
        if (lane >= d) x += y;
    }
    if (lane < nb) bs[lane] = x - v;   // exclusive
}

__global__ __launch_bounds__(256) void scan3(int* __restrict__ histC,
                                             int* __restrict__ histR,
                                             const int* __restrict__ bsum, int n) {
    int* a = blockIdx.y ? histR : histC;
    const int* bs = bsum + blockIdx.y * 64;
    int i = blockIdx.x * 256 + threadIdx.x;
    if (i < n) a[i] += bs[i >> 10];
}

// ---- stage 3: radix scatter into bin-sorted order (LDS cursors) ----
__global__ __launch_bounds__(256) void scatter_k(const int* __restrict__ erow,
                                                 const int* __restrict__ ecol,
                                                 const int* __restrict__ scC,
                                                 const int* __restrict__ scR,
                                                 uint* __restrict__ colSorted,
                                                 int* __restrict__ rowSorted) {
    __shared__ int curC[NBINS], curR[NBINS];
    int t = threadIdx.x, b = blockIdx.x;
    if (t < NBINS) {
        curC[t] = scC[t * G_BLOCKS + b];
        curR[t] = scR[t * G_BLOCKS + b];
    }
    __syncthreads();
    int s = b * EPB;
    for (int i = s + t; i < s + EPB; i += 256) {
        int r = erow[i], c = ecol[i];
        int p = atomicAdd(&curC[c >> 8], 1);
        colSorted[p] = (uint)r | ((uint)c << 16);   // both < 50000 < 2^16
        int q = atomicAdd(&curR[r >> 8], 1);
        rowSorted[q] = r;
    }
}

// ---- stage 4a: fine row counts -> disv (deg^-0.5 with self loop) ----
__global__ __launch_bounds__(256) void fine_row(const int* __restrict__ rowSorted,
                                                const int* __restrict__ scR,
                                                float* __restrict__ disv) {
    __shared__ int cnt[256];
    int bin = blockIdx.x, t = threadIdx.x;
    int base = scR[bin * G_BLOCKS];
    int end  = (bin == NBINS - 1) ? N_EDGES : scR[(bin + 1) * G_BLOCKS];
    cnt[t] = 0;
    __syncthreads();
    for (int i = base + t; i < end; i += 256)
        atomicAdd(&cnt[rowSorted[i] & 255], 1);
    __syncthreads();
    int node = bin * 256 + t;
    if (node < N_NODES) disv[node] = rsqrtf((float)(cnt[t] + 1));
}

// ---- stage 4b: fine col pass -> offs (CSR) + epack {fp16 norm | src} ----
__global__ __launch_bounds__(256) void fine_col(const uint* __restrict__ colSorted,
                                                const int* __restrict__ scC,
                                                const float* __restrict__ disv,
                                                int* __restrict__ offs,
                                                uint* __restrict__ epack) {
    __shared__ int cnt[256];
    __shared__ int excl[256];
    __shared__ int wt[4];
    int bin = blockIdx.x, t = threadIdx.x;
    int base = scC[bin * G_BLOCKS];
    int end  = (bin == NBINS - 1) ? N_EDGES : scC[(bin + 1) * G_BLOCKS];
    cnt[t] = 0;
    __syncthreads();
    for (int i = base + t; i < end; i += 256)
        atomicAdd(&cnt[(colSorted[i] >> 16) & 255], 1);
    __syncthreads();
    // exclusive scan of cnt[256]
    int lane = t & 63, w = t >> 6;
    int v = cnt[t];
    int x = v;
#pragma unroll
    for (int d = 1; d < 64; d <<= 1) {
        int y = __shfl_up(x, d);
        if (lane >= d) x += y;
    }
    if (lane == 63) wt[w] = x;
    __syncthreads();
    int wo = 0;
    for (int u = 0; u < w; u++) wo += wt[u];
    excl[t] = wo + x - v;
    cnt[t] = 0;              // reuse as fill cursor
    int node = bin * 256 + t;
    if (node <= N_NODES) offs[node] = base + wo + x - v;  // sentinel at 50000 ok
    __syncthreads();
    for (int i = base + t; i < end; i += 256) {
        uint pv = colSorted[i];
        int cl = (pv >> 16) & 255;
        int src = (int)(pv & 0xFFFFu);
        int p = base + excl[cl] + atomicAdd(&cnt[cl], 1);
        ushort nb_ = __half_as_ushort(__float2half_rn(disv[src]));
        epack[p] = ((uint)nb_ << 16) | (uint)src;
    }
}

// ---- transpose+cast both weight matrices in one launch ----
__global__ __launch_bounds__(256) void transpose_w2(const float* __restrict__ W1,
                                                    const float* __restrict__ W2,
                                                    ushort* __restrict__ w1t,
                                                    ushort* __restrict__ w2t) {
    int i = blockIdx.x * 256 + threadIdx.x;
    if (i < N_IN * 64) {
        int k = i >> 6, n = i & 63;
        w1t[n * N_IN + k] = f2bf(W1[i]);
    } else if (i < N_IN * 64 + HIDDEN * 64) {
        int j = i - N_IN * 64;
        int k = j >> 6, n = j & 63;
        w2t[n * HIDDEN + k] = f2bf(W2[j]);
    }
}

// ---- MFMA GEMM: C[M,64](bf16) = A[M,K] @ WT[64,K](bf16) + bias ----
template <bool ABF16>
__global__ __launch_bounds__(256) void gemm_mfma(const void* __restrict__ Av,
                                                 const ushort* __restrict__ WT,
                                                 const float* __restrict__ bias,
                                                 ushort* __restrict__ C,
                                                 int M, int K) {
    __shared__ ushort Asb[64][72];   // [m][k], +8 pad
    __shared__ ushort Bsb[64][72];   // [n][k], +8 pad
    int t = threadIdx.x;
    int w = t >> 6, lane = t & 63;
    int wm = w >> 1, wn = w & 1;           // 2x2 wave grid
    int lr = lane & 15, lg = lane >> 4;    // frag row, k-group
    int blockRow = blockIdx.x * 64;

    f32x4 acc[2][2];
#pragma unroll
    for (int i = 0; i < 2; i++)
#pragma unroll
        for (int j = 0; j < 2; j++) acc[i][j] = (f32x4){0.f, 0.f, 0.f, 0.f};

    for (int kk = 0; kk < K; kk += 64) {
#pragma unroll
        for (int u = 0; u < 2; u++) {
            int idx = t + u * 256;
            int m = idx >> 3;
            int k8 = (idx & 7) * 8;
            int row = blockRow + m;
            short8_t s;
            if (ABF16) {
                const ushort* A16 = (const ushort*)Av;
                if (row < M) s = *(const short8_t*)(A16 + (size_t)row * K + kk + k8);
                else s = (short8_t){0,0,0,0,0,0,0,0};
            } else {
                const float* A32 = (const float*)Av;
                float4 a0, a1;
                if (row < M) {
                    const float* p = A32 + (size_t)row * K + kk + k8;
                    a0 = *(const float4*)p;
                    a1 = *(const float4*)(p + 4);
                } else {
                    a0 = make_float4(0.f, 0.f, 0.f, 0.f);
                    a1 = a0;
                }
                s[0] = (short)f2bf(a0.x); s[1] = (short)f2bf(a0.y);
                s[2] = (short)f2bf(a0.z); s[3] = (short)f2bf(a0.w);
                s[4] = (short)f2bf(a1.x); s[5] = (short)f2bf(a1.y);
                s[6] = (short)f2bf(a1.z); s[7] = (short)f2bf(a1.w);
            }
            *(short8_t*)&Asb[m][k8] = s;
        }
#pragma unroll
        for (int u = 0; u < 2; u++) {
            int idx = t + u * 256;
            int n = idx >> 3;
            int k8 = (idx & 7) * 8;
            short8_t vv = *(const short8_t*)(WT + (size_t)n * K + kk + k8);
            *(short8_t*)&Bsb[n][k8] = vv;
        }
        __syncthreads();
#pragma unroll
        for (int ks = 0; ks < 2; ks++) {
            int k0 = ks * 32 + lg * 8;
            short8_t af[2], bf_[2];
#pragma unroll
            for (int mi = 0; mi < 2; mi++)
                af[mi] = *(const short8_t*)&Asb[wm * 32 + mi * 16 + lr][k0];
#pragma unroll
            for (int ni = 0; ni < 2; ni++)
                bf_[ni] = *(const short8_t*)&Bsb[wn * 32 + ni * 16 + lr][k0];
#pragma unroll
            for (int mi = 0; mi < 2; mi++)
#pragma unroll
                for (int ni = 0; ni < 2; ni++)
                    acc[mi][ni] = __builtin_amdgcn_mfma_f32_16x16x32_bf16(
                        af[mi], bf_[ni], acc[mi][ni], 0, 0, 0);
        }
        __syncthreads();
    }
#pragma unroll
    for (int mi = 0; mi < 2; mi++) {
#pragma unroll
        for (int ni = 0; ni < 2; ni++) {
            int col = wn * 32 + ni * 16 + lr;
            float bv = bias[col];
#pragma unroll
            for (int r = 0; r < 4; r++) {
                int row = blockRow + wm * 32 + mi * 16 + lg * 4 + r;
                if (row < M) C[(size_t)row * 64 + col] = f2bf(acc[mi][ni][r] + bv);
            }
        }
    }
}

// ---- wide aggregation: one wave per node; lane = (edge g = lane>>3, chunk c = lane&7)
// One uint4 load fetches 8 rows' 16B chunks (1KB/wave-instr). Two dependent
// memory rounds total for d<=32; butterfly-reduce over g at the end.
// HEAD=0: +relu, bf16 store. HEAD=1: fused output head + log_softmax.
template <int HEAD>
__global__ __launch_bounds__(256) void agg_wide(const ushort* __restrict__ H,
                                                const int* __restrict__ offs,
                                                const uint* __restrict__ epack,
                                                const float* __restrict__ disv,
                                                ushort* __restrict__ outH,
                                                const float* __restrict__ Wo,
                                                const float* __restrict__ bo,
                                                float* __restrict__ outL) {
    __shared__ float Wl[HEAD ? HIDDEN * N_CLASSES : 1];
    __shared__ float bl[HEAD ? N_CLASSES : 1];
    if (HEAD) {
        for (int i = threadIdx.x; i < HIDDEN * N_CLASSES; i += 256) Wl[i] = Wo[i];
        if (threadIdx.x < N_CLASSES) bl[threadIdx.x] = bo[threadIdx.x];
        __syncthreads();
    }
    int wv = (blockIdx.x * 256 + threadIdx.x) >> 6;
    int lane = threadIdx.x & 63;
    if (wv >= N_NODES) return;
    int c = lane & 7, g = lane >> 3;
    int s = offs[wv], e = offs[wv + 1];
    float dn = disv[wv];
    int cap = (e > s) ? (e - 1) : 0;

    // ---- round 1: self-row chunk + all epack batch words (independent) ----
    uint4 sf = *(const uint4*)(H + (size_t)wv * 64 + c * 8);
    int i0 = s + g, i1 = s + 8 + g, i2 = s + 16 + g, i3 = s + 24 + g;
    uint ep0 = epack[min(i0, cap)];
    uint ep1 = epack[min(i1, cap)];
    uint ep2 = epack[min(i2, cap)];
    uint ep3 = epack[min(i3, cap)];

    // ---- round 2: all row gathers (independent) ----
    uint4 h0 = *(const uint4*)(H + (size_t)(ep0 & 0xFFFFu) * 64 + c * 8);
    uint4 h1 = *(const uint4*)(H + (size_t)(ep1 & 0xFFFFu) * 64 + c * 8);
    uint4 h2 = *(const uint4*)(H + (size_t)(ep2 & 0xFFFFu) * 64 + c * 8);
    uint4 h3 = *(const uint4*)(H + (size_t)(ep3 & 0xFFFFu) * 64 + c * 8);

    float acc[8];
#pragma unroll
    for (int j = 0; j < 8; j++) acc[j] = 0.f;

#define ACCUM(hh, ww) do { \
    float _w = (ww); \
    acc[0] = fmaf(_w, __uint_as_float((hh).x << 16), acc[0]); \
    acc[1] = fmaf(_w, __uint_as_float((hh).x & 0xFFFF0000u), acc[1]); \
    acc[2] = fmaf(_w, __uint_as_float((hh).y << 16), acc[2]); \
    acc[3] = fmaf(_w, __uint_as_float((hh).y & 0xFFFF0000u), acc[3]); \
    acc[4] = fmaf(_w, __uint_as_float((hh).z << 16), acc[4]); \
    acc[5] = fmaf(_w, __uint_as_float((hh).z & 0xFFFF0000u), acc[5]); \
    acc[6] = fmaf(_w, __uint_as_float((hh).w << 16), acc[6]); \
    acc[7] = fmaf(_w, __uint_as_float((hh).w & 0xFFFF0000u), acc[7]); \
} while (0)

#define EPW(ep, ii) (((ii) < e) ? dn * __half2float(__ushort_as_half((ushort)((ep) >> 16))) : 0.f)

    ACCUM(h0, EPW(ep0, i0));
    ACCUM(h1, EPW(ep1, i1));
    ACCUM(h2, EPW(ep2, i2));
    ACCUM(h3, EPW(ep3, i3));

    // rare fallback: degree > 32 (Poisson(16) tail, ~1e-4 of nodes)
    for (int i = s + 32; i < e; i += 8) {
        int idx = i + g;
        uint ep = epack[min(idx, cap)];
        uint4 hh = *(const uint4*)(H + (size_t)(ep & 0xFFFFu) * 64 + c * 8);
        ACCUM(hh, EPW(ep, idx));
    }

    // ---- butterfly reduce over g (lanes differing in bits 3..5) ----
#pragma unroll
    for (int m = 8; m < 64; m <<= 1)
#pragma unroll
        for (int j = 0; j < 8; j++) acc[j] += __shfl_xor(acc[j], m);

    // self loop (add once, after reduction)
    ACCUM(sf, dn * dn);

    if (!HEAD) {
        if (g == 0) {
            short8_t sv;
#pragma unroll
            for (int j = 0; j < 8; j++) sv[j] = (short)f2bf(fmaxf(acc[j], 0.f));
            *(short8_t*)(outH + (size_t)wv * 64 + c * 8) = sv;
        }
    } else {
        // head: logits = h @ Wo + bo; h[k] lives in lane (k>>3), reg (k&7)
        float accL = (lane < N_CLASSES) ? bl[lane] : -1e30f;
#pragma unroll
        for (int k = 0; k < HIDDEN; k++) {
            float xb = __shfl(acc[k & 7], k >> 3);
            if (lane < N_CLASSES) accL = fmaf(xb, Wl[k * N_CLASSES + lane], accL);
        }
        float mx = accL;
#pragma unroll
        for (int d = 32; d; d >>= 1) mx = fmaxf(mx, __shfl_xor(mx, d));
        float ex = (lane < N_CLASSES) ? expf(accL - mx) : 0.f;
        float sm = ex;
#pragma unroll
        for (int d = 32; d; d >>= 1) sm += __shfl_xor(sm, d);
        if (lane < N_CLASSES)
            outL[(size_t)wv * N_CLASSES + lane] = accL - mx - logf(sm);
    }
#undef ACCUM
#undef EPW
}

extern "C" void kernel_launch(void* const* d_in, const int* in_sizes, int n_in,
                              void* d_out, int out_size, void* d_ws, size_t ws_size,
                              hipStream_t stream) {
    const float* x  = (const float*)d_in[0];
    const float* W1 = (const float*)d_in[1];
    const float* b1 = (const float*)d_in[2];
    const float* W2 = (const float*)d_in[3];
    const float* b2 = (const float*)d_in[4];
    const float* Wo = (const float*)d_in[5];
    const float* bo = (const float*)d_in[6];
    const int* ei   = (const int*)d_in[7];
    const int* erow = ei;
    const int* ecol = ei + N_EDGES;

    char* ws = (char*)d_ws;
    ushort* h_a   = (ushort*)(ws + OFF_HA);
    ushort* h_b   = (ushort*)(ws + OFF_HB);
    float* disv   = (float*)(ws + OFF_DIS);
    int*   offs   = (int*)(ws + OFF_OFFS);
    int*   histC  = (int*)(ws + OFF_HISTC);
    int*   histR  = (int*)(ws + OFF_HISTR);
    int*   bsum   = (int*)(ws + OFF_BSUM);
    uint*  colS   = (uint*)(ws + OFF_COLS);
    int*   rowS   = (int*)(ws + OFF_ROWS);
    uint*  epack  = (uint*)(ws + OFF_EPACK);
    ushort* w1t   = (ushort*)(ws + OFF_W1T);
    ushort* w2t   = (ushort*)(ws + OFF_W2T);
    float* outp   = (float*)d_out;

    // graph build: coarse hist -> scans (C,R fused via gridDim.y) -> scatter -> fine
    hist_k<<<G_BLOCKS, 256, 0, stream>>>(erow, ecol, histC, histR);
    scan1<<<dim3(SCAN_NB, 2), 256, 0, stream>>>(histC, histR, bsum, SCAN_N);
    scan2<<<2, 64, 0, stream>>>(bsum, SCAN_NB);
    scan3<<<dim3((SCAN_N + 255) / 256, 2), 256, 0, stream>>>(histC, histR, bsum, SCAN_N);
    scatter_k<<<G_BLOCKS, 256, 0, stream>>>(erow, ecol, histC, histR, colS, rowS);
    fine_row<<<NBINS, 256, 0, stream>>>(rowS, histR, disv);
    fine_col<<<NBINS, 256, 0, stream>>>(colS, histC, disv, offs, epack);

    // weights -> bf16 transposed (one launch)
    transpose_w2<<<(N_IN * 64 + HIDDEN * 64 + 255) / 256, 256, 0, stream>>>(W1, W2, w1t, w2t);

    // conv1: lin (MFMA bf16) -> aggregate(+relu)
    gemm_mfma<false><<<(N_NODES + 63) / 64, 256, 0, stream>>>(x, w1t, b1, h_a, N_NODES, N_IN);
    agg_wide<0><<<(N_NODES + 3) / 4, 256, 0, stream>>>(h_a, offs, epack, disv, h_b,
                                                       nullptr, nullptr, nullptr);
    // conv2: lin -> fused aggregate + head + log_softmax
    gemm_mfma<true><<<(N_NODES + 63) / 64, 256, 0, stream>>>(h_b, w2t, b2, h_a, N_NODES, HIDDEN);
    agg_wide<1><<<(N_NODES + 3) / 4, 256, 0, stream>>>(h_a, offs, epack, disv, nullptr,
                                                       Wo, bo, outp);
}

// Round 7
// 139.762 us; speedup vs baseline: 1.2510x; 1.2510x over previous
//
#include <hip/hip_runtime.h>
#include <hip/hip_fp16.h>
#include <cstdint>

// Problem constants (from reference)
#define N_NODES   50000
#define N_IN      512
#define HIDDEN    64
#define N_CLASSES 40
#define N_EDGES   800000

// Radix build parameters
#define G_BLOCKS  200                 // blocks in hist/scatter passes
#define EPB       4000                // edges per block (G_BLOCKS*EPB == N_EDGES)
#define NBINS     196                 // ceil(50000/256), bin = node >> 8
#define SCAN_N    (NBINS * G_BLOCKS)  // 39200
#define SCAN_NB   ((SCAN_N + 1023) / 1024)   // 39

// Workspace layout (byte offsets, 16B-aligned)
#define OFF_HA    0u          // 50000*64*2 bf16 = 6,400,000
#define OFF_HB    6400000u    // 6,400,000
#define OFF_DIS   12800000u   // 50000 floats = 200,000
#define OFF_OFFS  13000000u   // 50001 ints = 200,004 -> pad 200,016
#define OFF_HISTC 13200016u   // 39200 ints = 156,800
#define OFF_HISTR 13356816u   // 39200 ints = 156,800
#define OFF_BSUM  13513616u   // 128 ints = 512
#define OFF_COLS  13514128u   // 800000 u32 packed (r | c<<16) = 3,200,000
#define OFF_ROWS  16714128u   // 800000 ints = 3,200,000
#define OFF_EPACK 19914128u   // 800000 u32 (fp16 fullnorm | src) = 3,200,000
#define OFF_W1T   23114128u   // 64*512 bf16 = 65,536
#define OFF_W2OT  23179664u   // 64*64 bf16 (W2@Wo)^T padded = 8,192
#define OFF_B2O   23187856u   // 64 floats = 256
// total ~23.2 MB

typedef __attribute__((ext_vector_type(8))) short short8_t;
typedef __attribute__((ext_vector_type(4))) float f32x4;

__device__ __forceinline__ ushort f2bf(float f) {
    uint u = __float_as_uint(f);
    uint r = (u + 0x7FFFu + ((u >> 16) & 1u)) >> 16;   // RNE
    return (ushort)r;
}
__device__ __forceinline__ float bf2f(ushort h) {
    return __uint_as_float((uint)h << 16);
}

// ---- stage 1: per-block coarse histograms (LDS only, no global atomics) ----
__global__ __launch_bounds__(256) void hist_k(const int* __restrict__ erow,
                                              const int* __restrict__ ecol,
                                              int* __restrict__ histC,
                                              int* __restrict__ histR) {
    __shared__ int hc[NBINS], hr[NBINS];
    int t = threadIdx.x, b = blockIdx.x;
    if (t < NBINS) { hc[t] = 0; hr[t] = 0; }
    __syncthreads();
    int s = b * EPB;
    for (int i = s + t; i < s + EPB; i += 256) {
        atomicAdd(&hc[ecol[i] >> 8], 1);
        atomicAdd(&hr[erow[i] >> 8], 1);
    }
    __syncthreads();
    if (t < NBINS) {
        histC[t * G_BLOCKS + b] = hc[t];   // [bin][block] layout for bin-major scan
        histR[t * G_BLOCKS + b] = hr[t];
    }
}

// ---- exclusive scan over histC (y=0) and histR (y=1), in-place ----
__global__ __launch_bounds__(256) void scan1(int* __restrict__ histC,
                                             int* __restrict__ histR,
                                             int* __restrict__ bsum, int n) {
    int* a  = blockIdx.y ? histR : histC;
    int* bs = bsum + blockIdx.y * 64;
    int t = threadIdx.x;
    int g = blockIdx.x * 1024 + t * 4;
    int v[4];
#pragma unroll
    for (int i = 0; i < 4; i++) v[i] = (g + i < n) ? a[g + i] : 0;
    int s = v[0] + v[1] + v[2] + v[3];
    int lane = t & 63, wid = t >> 6;
    int x = s;
#pragma unroll
    for (int d = 1; d < 64; d <<= 1) {
        int y = __shfl_up(x, d);
        if (lane >= d) x += y;
    }
    __shared__ int wt[4];
    if (lane == 63) wt[wid] = x;
    __syncthreads();
    int wo = 0;
    for (int w = 0; w < wid; w++) wo += wt[w];
    int run = wo + x - s;
#pragma unroll
    for (int i = 0; i < 4; i++) {
        if (g + i < n) a[g + i] = run;
        run += v[i];
    }
    if (t == 255) bs[blockIdx.x] = wo + x;
}

__global__ void scan2(int* bsum, int nb) {
    int* bs = bsum + blockIdx.x * 64;
    int lane = threadIdx.x;   // 64 threads
    int v = (lane < nb) ? bs[lane] : 0;
    int x = v;
#pragma unroll
    for (int d = 1; d < 64; d <<= 1) {
        int y = __shfl_up(x, d);
        if (lane >= d) x += y;
    }
    if (lane < nb) bs[lane] = x - v;   // exclusive
}

__global__ __launch_bounds__(256) void scan3(int* __restrict__ histC,
                                             int* __restrict__ histR,
                                             const int* __restrict__ bsum, int n) {
    int* a = blockIdx.y ? histR : histC;
    const int* bs = bsum + blockIdx.y * 64;
    int i = blockIdx.x * 256 + threadIdx.x;
    if (i < n) a[i] += bs[i >> 10];
}

// ---- stage 3: radix scatter into bin-sorted order (LDS cursors) ----
__global__ __launch_bounds__(256) void scatter_k(const int* __restrict__ erow,
                                                 const int* __restrict__ ecol,
                                                 const int* __restrict__ scC,
                                                 const int* __restrict__ scR,
                                                 uint* __restrict__ colSorted,
                                                 int* __restrict__ rowSorted) {
    __shared__ int curC[NBINS], curR[NBINS];
    int t = threadIdx.x, b = blockIdx.x;
    if (t < NBINS) {
        curC[t] = scC[t * G_BLOCKS + b];
        curR[t] = scR[t * G_BLOCKS + b];
    }
    __syncthreads();
    int s = b * EPB;
    for (int i = s + t; i < s + EPB; i += 256) {
        int r = erow[i], c = ecol[i];
        int p = atomicAdd(&curC[c >> 8], 1);
        colSorted[p] = (uint)r | ((uint)c << 16);   // both < 50000 < 2^16
        int q = atomicAdd(&curR[r >> 8], 1);
        rowSorted[q] = r;
    }
}

// ---- stage 4a: fine row counts -> disv (deg^-0.5 with self loop) ----
__global__ __launch_bounds__(256) void fine_row(const int* __restrict__ rowSorted,
                                                const int* __restrict__ scR,
                                                float* __restrict__ disv) {
    __shared__ int cnt[256];
    int bin = blockIdx.x, t = threadIdx.x;
    int base = scR[bin * G_BLOCKS];
    int end  = (bin == NBINS - 1) ? N_EDGES : scR[(bin + 1) * G_BLOCKS];
    cnt[t] = 0;
    __syncthreads();
    for (int i = base + t; i < end; i += 256)
        atomicAdd(&cnt[rowSorted[i] & 255], 1);
    __syncthreads();
    int node = bin * 256 + t;
    if (node < N_NODES) disv[node] = rsqrtf((float)(cnt[t] + 1));
}

// ---- stage 4b: fine col pass -> offs (CSR) + epack {fp16 fullnorm | src} ----
__global__ __launch_bounds__(256) void fine_col(const uint* __restrict__ colSorted,
                                                const int* __restrict__ scC,
                                                const float* __restrict__ disv,
                                                int* __restrict__ offs,
                                                uint* __restrict__ epack) {
    __shared__ int cnt[256];
    __shared__ int excl[256];
    __shared__ int wt[4];
    __shared__ float dvs[256];
    int bin = blockIdx.x, t = threadIdx.x;
    int base = scC[bin * G_BLOCKS];
    int end  = (bin == NBINS - 1) ? N_EDGES : scC[(bin + 1) * G_BLOCKS];
    cnt[t] = 0;
    int node = bin * 256 + t;
    dvs[t] = (node < N_NODES) ? disv[node] : 0.f;
    __syncthreads();
    for (int i = base + t; i < end; i += 256)
        atomicAdd(&cnt[(colSorted[i] >> 16) & 255], 1);
    __syncthreads();
    // exclusive scan of cnt[256]
    int lane = t & 63, w = t >> 6;
    int v = cnt[t];
    int x = v;
#pragma unroll
    for (int d = 1; d < 64; d <<= 1) {
        int y = __shfl_up(x, d);
        if (lane >= d) x += y;
    }
    if (lane == 63) wt[w] = x;
    __syncthreads();
    int wo = 0;
    for (int u = 0; u < w; u++) wo += wt[u];
    excl[t] = wo + x - v;
    cnt[t] = 0;              // reuse as fill cursor
    if (node <= N_NODES) offs[node] = base + wo + x - v;  // sentinel at 50000 ok
    __syncthreads();
    for (int i = base + t; i < end; i += 256) {
        uint pv = colSorted[i];
        int cl = (pv >> 16) & 255;
        int src = (int)(pv & 0xFFFFu);
        int p = base + excl[cl] + atomicAdd(&cnt[cl], 1);
        float nrm = disv[src] * dvs[cl];          // full norm (src*dst)
        ushort nb_ = __half_as_ushort(__float2half_rn(nrm));
        epack[p] = ((uint)nb_ << 16) | (uint)src;
    }
}

// ---- setup: W1 transpose->bf16; W2o=(W2@Wo)^T bf16 padded; b2o=b2@Wo ----
__global__ __launch_bounds__(256) void fold_w(const float* __restrict__ W1,
                                              const float* __restrict__ W2,
                                              const float* __restrict__ Wo,
                                              const float* __restrict__ b2,
                                              ushort* __restrict__ w1t,
                                              ushort* __restrict__ w2ot,
                                              float* __restrict__ b2o) {
    int i = blockIdx.x * 256 + threadIdx.x;
    if (i < N_IN * 64) {
        int k = i >> 6, n = i & 63;
        w1t[n * N_IN + k] = f2bf(W1[i]);
    } else if (i < N_IN * 64 + 64 * 64) {
        int j = i - N_IN * 64;
        int k = j >> 6, n = j & 63;       // k: conv2 input feat, n: class (pad 64)
        float v = 0.f;
        if (n < N_CLASSES)
            for (int jj = 0; jj < HIDDEN; jj++)
                v += W2[k * HIDDEN + jj] * Wo[jj * N_CLASSES + n];
        w2ot[n * HIDDEN + k] = f2bf(v);
    } else if (i < N_IN * 64 + 64 * 64 + 64) {
        int c = i - N_IN * 64 - 64 * 64;
        float v = 0.f;
        if (c < N_CLASSES)
            for (int jj = 0; jj < HIDDEN; jj++)
                v += b2[jj] * Wo[jj * N_CLASSES + c];
        b2o[c] = v;
    }
}

// ---- MFMA GEMM: C[M,64](bf16) = A[M,K] @ WT[64,K](bf16) + bias ----
template <bool ABF16>
__global__ __launch_bounds__(256) void gemm_mfma(const void* __restrict__ Av,
                                                 const ushort* __restrict__ WT,
                                                 const float* __restrict__ bias,
                                                 ushort* __restrict__ C,
                                                 int M, int K) {
    __shared__ ushort Asb[64][72];   // [m][k], +8 pad
    __shared__ ushort Bsb[64][72];   // [n][k], +8 pad
    int t = threadIdx.x;
    int w = t >> 6, lane = t & 63;
    int wm = w >> 1, wn = w & 1;           // 2x2 wave grid
    int lr = lane & 15, lg = lane >> 4;    // frag row, k-group
    int blockRow = blockIdx.x * 64;

    f32x4 acc[2][2];
#pragma unroll
    for (int i = 0; i < 2; i++)
#pragma unroll
        for (int j = 0; j < 2; j++) acc[i][j] = (f32x4){0.f, 0.f, 0.f, 0.f};

    for (int kk = 0; kk < K; kk += 64) {
#pragma unroll
        for (int u = 0; u < 2; u++) {
            int idx = t + u * 256;
            int m = idx >> 3;
            int k8 = (idx & 7) * 8;
            int row = blockRow + m;
            short8_t s;
            if (ABF16) {
                const ushort* A16 = (const ushort*)Av;
                if (row < M) s = *(const short8_t*)(A16 + (size_t)row * K + kk + k8);
                else s = (short8_t){0,0,0,0,0,0,0,0};
            } else {
                const float* A32 = (const float*)Av;
                float4 a0, a1;
                if (row < M) {
                    const float* p = A32 + (size_t)row * K + kk + k8;
                    a0 = *(const float4*)p;
                    a1 = *(const float4*)(p + 4);
                } else {
                    a0 = make_float4(0.f, 0.f, 0.f, 0.f);
                    a1 = a0;
                }
                s[0] = (short)f2bf(a0.x); s[1] = (short)f2bf(a0.y);
                s[2] = (short)f2bf(a0.z); s[3] = (short)f2bf(a0.w);
                s[4] = (short)f2bf(a1.x); s[5] = (short)f2bf(a1.y);
                s[6] = (short)f2bf(a1.z); s[7] = (short)f2bf(a1.w);
            }
            *(short8_t*)&Asb[m][k8] = s;
        }
#pragma unroll
        for (int u = 0; u < 2; u++) {
            int idx = t + u * 256;
            int n = idx >> 3;
            int k8 = (idx & 7) * 8;
            short8_t vv = *(const short8_t*)(WT + (size_t)n * K + kk + k8);
            *(short8_t*)&Bsb[n][k8] = vv;
        }
        __syncthreads();
#pragma unroll
        for (int ks = 0; ks < 2; ks++) {
            int k0 = ks * 32 + lg * 8;
            short8_t af[2], bf_[2];
#pragma unroll
            for (int mi = 0; mi < 2; mi++)
                af[mi] = *(const short8_t*)&Asb[wm * 32 + mi * 16 + lr][k0];
#pragma unroll
            for (int ni = 0; ni < 2; ni++)
                bf_[ni] = *(const short8_t*)&Bsb[wn * 32 + ni * 16 + lr][k0];
#pragma unroll
            for (int mi = 0; mi < 2; mi++)
#pragma unroll
                for (int ni = 0; ni < 2; ni++)
                    acc[mi][ni] = __builtin_amdgcn_mfma_f32_16x16x32_bf16(
                        af[mi], bf_[ni], acc[mi][ni], 0, 0, 0);
        }
        __syncthreads();
    }
#pragma unroll
    for (int mi = 0; mi < 2; mi++) {
#pragma unroll
        for (int ni = 0; ni < 2; ni++) {
            int col = wn * 32 + ni * 16 + lr;
            float bv = bias[col];
#pragma unroll
            for (int r = 0; r < 4; r++) {
                int row = blockRow + wm * 32 + mi * 16 + lg * 4 + r;
                if (row < M) C[(size_t)row * 64 + col] = f2bf(acc[mi][ni][r] + bv);
            }
        }
    }
}

// ---- aggregation v3: wave per node, lane = feature; everything scalar except
// the one coalesced row-gather per edge. HEAD=0: relu+bf16 store; HEAD=1:
// +bo then log_softmax (head GEMM already folded into conv2 weights).
template <int HEAD>
__global__ __launch_bounds__(256) void agg_v3(const ushort* __restrict__ H,
                                              const int* __restrict__ offs,
                                              const uint* __restrict__ epack,
                                              const float* __restrict__ disv,
                                              ushort* __restrict__ outH,
                                              const float* __restrict__ bo,
                                              float* __restrict__ outL) {
    int wv = (blockIdx.x * 256 + threadIdx.x) >> 6;
    int lane = threadIdx.x & 63;
    wv = __builtin_amdgcn_readfirstlane(wv);   // wave-uniform -> SGPR
    if (wv >= N_NODES) return;
    int s = offs[wv], e = offs[wv + 1];        // s_load
    float dn = disv[wv];                       // s_load
    float acc = dn * dn * bf2f(H[(size_t)wv * 64 + lane]);   // self loop

    for (int i = s; i < e; i += 8) {
        uint ep[8];
        int cap = e - 1;
#pragma unroll
        for (int u = 0; u < 8; u++)
            ep[u] = epack[min(i + u, cap)];    // uniform -> s_load
        float hv[8];
#pragma unroll
        for (int u = 0; u < 8; u++)
            hv[u] = bf2f(H[(size_t)(ep[u] & 0xFFFFu) * 64 + lane]);  // coalesced row
#pragma unroll
        for (int u = 0; u < 8; u++) {
            uint wb = (i + u < e) ? (ep[u] >> 16) : 0u;   // scalar select
            float w = __half2float(__ushort_as_half((ushort)wb));
            acc = fmaf(w, hv[u], acc);
        }
    }

    if (!HEAD) {
        outH[(size_t)wv * 64 + lane] = f2bf(fmaxf(acc, 0.f));
    } else {
        float accL = (lane < N_CLASSES) ? acc + bo[lane] : -1e30f;
        float mx = accL;
#pragma unroll
        for (int d = 32; d; d >>= 1) mx = fmaxf(mx, __shfl_xor(mx, d));
        float ex = (lane < N_CLASSES) ? expf(accL - mx) : 0.f;
        float sm = ex;
#pragma unroll
        for (int d = 32; d; d >>= 1) sm += __shfl_xor(sm, d);
        if (lane < N_CLASSES)
            outL[(size_t)wv * N_CLASSES + lane] = accL - mx - logf(sm);
    }
}

extern "C" void kernel_launch(void* const* d_in, const int* in_sizes, int n_in,
                              void* d_out, int out_size, void* d_ws, size_t ws_size,
                              hipStream_t stream) {
    const float* x  = (const float*)d_in[0];
    const float* W1 = (const float*)d_in[1];
    const float* b1 = (const float*)d_in[2];
    const float* W2 = (const float*)d_in[3];
    const float* b2 = (const float*)d_in[4];
    const float* Wo = (const float*)d_in[5];
    const float* bo = (const float*)d_in[6];
    const int* ei   = (const int*)d_in[7];
    const int* erow = ei;
    const int* ecol = ei + N_EDGES;

    char* ws = (char*)d_ws;
    ushort* h_a   = (ushort*)(ws + OFF_HA);
    ushort* h_b   = (ushort*)(ws + OFF_HB);
    float* disv   = (float*)(ws + OFF_DIS);
    int*   offs   = (int*)(ws + OFF_OFFS);
    int*   histC  = (int*)(ws + OFF_HISTC);
    int*   histR  = (int*)(ws + OFF_HISTR);
    int*   bsum   = (int*)(ws + OFF_BSUM);
    uint*  colS   = (uint*)(ws + OFF_COLS);
    int*   rowS   = (int*)(ws + OFF_ROWS);
    uint*  epack  = (uint*)(ws + OFF_EPACK);
    ushort* w1t   = (ushort*)(ws + OFF_W1T);
    ushort* w2ot  = (ushort*)(ws + OFF_W2OT);
    float* b2o    = (float*)(ws + OFF_B2O);
    float* outp   = (float*)d_out;

    // graph build: coarse hist -> scans (C,R fused via gridDim.y) -> scatter -> fine
    hist_k<<<G_BLOCKS, 256, 0, stream>>>(erow, ecol, histC, histR);
    scan1<<<dim3(SCAN_NB, 2), 256, 0, stream>>>(histC, histR, bsum, SCAN_N);
    scan2<<<2, 64, 0, stream>>>(bsum, SCAN_NB);
    scan3<<<dim3((SCAN_N + 255) / 256, 2), 256, 0, stream>>>(histC, histR, bsum, SCAN_N);
    scatter_k<<<G_BLOCKS, 256, 0, stream>>>(erow, ecol, histC, histR, colS, rowS);
    fine_row<<<NBINS, 256, 0, stream>>>(rowS, histR, disv);
    fine_col<<<NBINS, 256, 0, stream>>>(colS, histC, disv, offs, epack);

    // setup: W1->bf16^T, W2o=(W2@Wo)^T bf16 (pad 64), b2o=b2@Wo
    fold_w<<<(N_IN * 64 + 64 * 64 + 64 + 255) / 256, 256, 0, stream>>>(
        W1, W2, Wo, b2, w1t, w2ot, b2o);

    // conv1: lin (MFMA bf16) -> aggregate(+relu)
    gemm_mfma<false><<<(N_NODES + 63) / 64, 256, 0, stream>>>(x, w1t, b1, h_a, N_NODES, N_IN);
    agg_v3<0><<<(N_NODES + 3) / 4, 256, 0, stream>>>(h_a, offs, epack, disv, h_b,
                                                     nullptr, nullptr);
    // conv2 (head folded): M = H_relu @ W2o + b2o  -> aggregate + bo + log_softmax
    gemm_mfma<true><<<(N_NODES + 63) / 64, 256, 0, stream>>>(h_b, w2ot, b2o, h_a, N_NODES, HIDDEN);
    agg_v3<1><<<(N_NODES + 3) / 4, 256, 0, stream>>>(h_a, offs, epack, disv, nullptr,
                                                     bo, outp);
}